// Round 7
// baseline (153.176 us; speedup 1.0000x reference)
//
#include <hip/hip_runtime.h>
#include <hip/hip_bf16.h>

#define N_Q   25000
#define M_S   25000
#define C_INV 128

typedef unsigned short ushortT;
typedef unsigned short us8 __attribute__((ext_vector_type(8)));
typedef unsigned short us4 __attribute__((ext_vector_type(4)));
typedef short s8v __attribute__((ext_vector_type(8)));
typedef float f32x4 __attribute__((ext_vector_type(4)));

#define GAS __attribute__((address_space(1)))
#define LAS __attribute__((address_space(3)))

__device__ __forceinline__ float b2f(ushortT u) {
    unsigned v = ((unsigned)u) << 16;
    return __builtin_bit_cast(float, v);
}
__device__ __forceinline__ ushortT f2b(float f) {
    __hip_bfloat16 h = __float2bfloat16(f);
    return __builtin_bit_cast(ushortT, h);
}
__device__ __forceinline__ s8v mk8(us4 a, us4 b) {
    us8 r;
    r[0] = a[0]; r[1] = a[1]; r[2] = a[2]; r[3] = a[3];
    r[4] = b[0]; r[5] = b[1]; r[6] = b[2]; r[7] = b[3];
    return __builtin_bit_cast(s8v, r);
}

// ---------------- kernel 1: x fp32 -> bf16 ----------------
__global__ void k_convert_x(const float* __restrict__ x, ushortT* __restrict__ xb) {
    int i = blockIdx.x * 256 + threadIdx.x;
    const int n4 = (M_S * C_INV) / 4;
    if (i >= n4) return;
    float4 v = ((const float4*)x)[i];
    us4 o;
    o[0] = f2b(v.x); o[1] = f2b(v.y); o[2] = f2b(v.z); o[3] = f2b(v.w);
    ((us4*)xb)[i] = o;
}

// ---------------- kernel 2: W fp32 -> permuted-K fragment-major bf16 (K padded 2048) ----------------
__global__ void k_build_wfrag2(const float* __restrict__ W, ushortT* __restrict__ wf) {
    int o = blockIdx.x * 256 + threadIdx.x;
    if (o >= 262144) return;                 // 2048 * 128
    int j   = o & 7;
    int l   = (o >> 3) & 63;
    int db  = (o >> 9) & 7;
    int ks  = o >> 12;                       // 0..63
    int p   = ks * 32 + ((l >> 4) * 8) + j;  // 0..2047
    int ci  = p >> 8;
    int rem = p & 255;
    int ls  = rem >> 2;
    int r   = rem & 3;
    int k   = (ls >> 4) * 4 + r;
    int c   = ci * 16 + (ls & 15);
    int d   = db * 16 + (l & 15);
    wf[o] = (k < 15) ? f2b(W[((size_t)k * 128 + c) * 128 + d]) : (ushortT)0;
}

// ---------------- kernel 2b: old wfrag layout (fallback path only) ----------------
__global__ void k_build_wfrag(const float* __restrict__ W, ushortT* __restrict__ wf) {
    int o = blockIdx.x * 256 + threadIdx.x;
    if (o >= 1920 * 128) return;
    int j  = o & 7;
    int l  = (o >> 3) & 63;
    int db = (o >> 9) & 7;
    int ks = o >> 12;
    int r  = ks * 32 + ((l >> 4) * 8) + j;
    int d  = db * 16 + (l & 15);
    wf[o] = f2b(W[r * 128 + d]);
}

// ---------------- zero out ----------------
__global__ void k_zero(float* __restrict__ out) {
    int i = blockIdx.x * 256 + threadIdx.x;
    if (i < (N_Q * 128) / 4)
        ((float4*)out)[i] = float4{0.f, 0.f, 0.f, 0.f};
}

// ================= K1 v7: stages A+B, LDS-staged gather + ds_read_b64_tr_b16 =================
// tr_b16 semantics (derived to reconcile m156/m162): effective read per lane =
// (vaddr & ~127) + ((vaddr & 127) >> 3) * 2 + j*32 bytes.  Column slot is 8 B wide,
// so the per-lane column address must be c*8 BYTES (= &s_x[...][c*4]), not c*2.
__global__ __launch_bounds__(256, 6) void k_ab(
    const float* __restrict__ qp, const float* __restrict__ sp,
    const int* __restrict__ nb, const float* __restrict__ kp,
    const ushortT* __restrict__ xbf, ushortT* __restrict__ wf_out)
{
    __shared__ __align__(16) ushortT s_w[8 * 512];    // 8 KB  [q][(h>>3)*128 + k*8 + (h&7)]
    __shared__ int s_idx[8 * 32];                     // 1 KB
    __shared__ __align__(16) ushortT s_x[4][2048];    // 16 KB: per-wave [ci'(4)][32 h][16 c]

    const int t   = threadIdx.x;
    const int l   = t & 63;
    const int w   = t >> 6;          // wave 0..3
    const int blk = blockIdx.x;      // 3125 blocks x 8 q = 25000 exactly

    // ---- Phase A: thread = (q = t>>5, h = t&31) ----
    {
        const int q  = t >> 5;
        const int h  = t & 31;
        const int qg = blk * 8 + q;
        const float qx = qp[qg * 3 + 0], qy = qp[qg * 3 + 1], qz = qp[qg * 3 + 2];
        int idx = nb[qg * 32 + h];
        const bool valid = ((unsigned)idx < (unsigned)M_S);
        const int idc = valid ? idx : 0;
        s_idx[q * 32 + h] = idc;
        float px, py, pz;
        if (valid) { px = sp[idc * 3]; py = sp[idc * 3 + 1]; pz = sp[idc * 3 + 2]; }
        else       { px = 1e6f; py = 1e6f; pz = 1e6f; }
        const float rx = px - qx, ry = py - qy, rz = pz - qz;
        #pragma unroll
        for (int k = 0; k < 15; ++k) {
            const float dx = rx - kp[k * 3 + 0];
            const float dy = ry - kp[k * 3 + 1];
            const float dz = rz - kp[k * 3 + 2];
            const float d2 = dx * dx + dy * dy + dz * dz;
            float wv = 1.0f - sqrtf(d2) * (1.0f / 1.2f);
            wv = (wv > 0.0f) ? wv : 0.0f;
            s_w[q * 512 + (h >> 3) * 128 + k * 8 + (h & 7)] = f2b(wv);
        }
        s_w[q * 512 + (h >> 3) * 128 + 15 * 8 + (h & 7)] = 0;
    }
    __syncthreads();

    const int g = l >> 4;
    const int c = l & 15;
    us4* wfo = (us4*)wf_out;

    // per-lane tr vaddr: tile base + g*256 B (row group) + c*8 B (column slot)
    LAS ushortT* trp = (LAS ushortT*)(void*)(&s_x[w][g * 128 + c * 4]);

    for (int qi = 0; qi < 2; ++qi) {
        const int q    = w * 2 + qi;
        const int qrow = blk * 8 + q;
        const s8v af   = *(const s8v*)(s_w + q * 512 + g * 128 + c * 8);
        const int myid = s_idx[q * 32 + (l >> 1)];
        const ushortT* srcb = xbf + (size_t)myid * 128 + (l & 1) * 8;

        #pragma unroll
        for (int hf = 0; hf < 2; ++hf) {
            // stage 4 ci'-planes: lane m -> h=m>>1, c8=(m&1)*8, dest elems m*8
            #pragma unroll
            for (int ci = 0; ci < 4; ++ci) {
                __builtin_amdgcn_global_load_lds(
                    (const GAS unsigned int*)(const void*)(srcb + (hf * 4 + ci) * 16),
                    (LAS unsigned int*)(void*)(&s_x[w][ci * 512]), 16, 0, 0);
            }
            asm volatile("s_waitcnt vmcnt(0)" ::: "memory");
            __builtin_amdgcn_sched_barrier(0);

            us4 ta0, tb0, ta1, tb1, ta2, tb2, ta3, tb3;
            asm volatile(
                "ds_read_b64_tr_b16 %0, %8 offset:0\n\t"
                "ds_read_b64_tr_b16 %1, %8 offset:128\n\t"
                "ds_read_b64_tr_b16 %2, %8 offset:1024\n\t"
                "ds_read_b64_tr_b16 %3, %8 offset:1152\n\t"
                "ds_read_b64_tr_b16 %4, %8 offset:2048\n\t"
                "ds_read_b64_tr_b16 %5, %8 offset:2176\n\t"
                "ds_read_b64_tr_b16 %6, %8 offset:3072\n\t"
                "ds_read_b64_tr_b16 %7, %8 offset:3200\n\t"
                "s_waitcnt lgkmcnt(0)"
                : "=&v"(ta0), "=&v"(tb0), "=&v"(ta1), "=&v"(tb1),
                  "=&v"(ta2), "=&v"(tb2), "=&v"(ta3), "=&v"(tb3)
                : "v"(trp));
            __builtin_amdgcn_sched_barrier(0);

            const s8v b0 = mk8(ta0, tb0);
            const s8v b1 = mk8(ta1, tb1);
            const s8v b2 = mk8(ta2, tb2);
            const s8v b3 = mk8(ta3, tb3);

            #pragma unroll
            for (int ci = 0; ci < 4; ++ci) {
                const s8v bf = (ci == 0) ? b0 : (ci == 1) ? b1 : (ci == 2) ? b2 : b3;
                f32x4 d = __builtin_amdgcn_mfma_f32_16x16x32_bf16(
                    af, bf, (f32x4){0.f, 0.f, 0.f, 0.f}, 0, 0, 0);
                us4 o;
                o[0] = f2b(d[0]); o[1] = f2b(d[1]); o[2] = f2b(d[2]); o[3] = f2b(d[3]);
                wfo[(size_t)qrow * 512 + (hf * 4 + ci) * 64 + l] = o;
            }
        }
    }
}

// ================= K2 v7: LDS-free GEMM, Q-tile 64, K-split 4, atomic reduce =================
__global__ __launch_bounds__(256, 6) void k_gemm(
    const ushortT* __restrict__ wf, const ushortT* __restrict__ wfrag,
    float* __restrict__ out)
{
    const int t    = threadIdx.x;
    const int l    = t & 63;
    const int w    = t >> 6;         // 0..3
    const int blk  = blockIdx.x;
    const int tile = blk >> 2;       // 0..390
    const int ksl  = blk & 3;        // K slice
    const int n0   = w * 2;
    const int c    = l & 15;
    const int g    = l >> 4;

    f32x4 a00 = {0,0,0,0}, a01 = {0,0,0,0};
    f32x4 a10 = {0,0,0,0}, a11 = {0,0,0,0};
    f32x4 a20 = {0,0,0,0}, a21 = {0,0,0,0};
    f32x4 a30 = {0,0,0,0}, a31 = {0,0,0,0};

    const ushortT* ap = wf + ((size_t)(tile * 64 + c)) * 2048 + g * 8;

    const int ks0 = ksl * 16;
    #pragma unroll 4
    for (int ks = ks0; ks < ks0 + 16; ++ks) {
        const s8v b0 = *(const s8v*)(wfrag + ((size_t)(ks * 8 + n0    ) * 64 + l) * 8);
        const s8v b1 = *(const s8v*)(wfrag + ((size_t)(ks * 8 + n0 + 1) * 64 + l) * 8);
        const s8v va0 = *(const s8v*)(ap + (size_t)0 * 32768 + ks * 32);
        const s8v va1 = *(const s8v*)(ap + (size_t)1 * 32768 + ks * 32);
        const s8v va2 = *(const s8v*)(ap + (size_t)2 * 32768 + ks * 32);
        const s8v va3 = *(const s8v*)(ap + (size_t)3 * 32768 + ks * 32);
        a00 = __builtin_amdgcn_mfma_f32_16x16x32_bf16(va0, b0, a00, 0, 0, 0);
        a01 = __builtin_amdgcn_mfma_f32_16x16x32_bf16(va0, b1, a01, 0, 0, 0);
        a10 = __builtin_amdgcn_mfma_f32_16x16x32_bf16(va1, b0, a10, 0, 0, 0);
        a11 = __builtin_amdgcn_mfma_f32_16x16x32_bf16(va1, b1, a11, 0, 0, 0);
        a20 = __builtin_amdgcn_mfma_f32_16x16x32_bf16(va2, b0, a20, 0, 0, 0);
        a21 = __builtin_amdgcn_mfma_f32_16x16x32_bf16(va2, b1, a21, 0, 0, 0);
        a30 = __builtin_amdgcn_mfma_f32_16x16x32_bf16(va3, b0, a30, 0, 0, 0);
        a31 = __builtin_amdgcn_mfma_f32_16x16x32_bf16(va3, b1, a31, 0, 0, 0);
    }

    #pragma unroll
    for (int qq = 0; qq < 4; ++qq) {
        const f32x4 v0 = (qq == 0) ? a00 : (qq == 1) ? a10 : (qq == 2) ? a20 : a30;
        const f32x4 v1 = (qq == 0) ? a01 : (qq == 1) ? a11 : (qq == 2) ? a21 : a31;
        #pragma unroll
        for (int r = 0; r < 4; ++r) {
            const int qrow = tile * 64 + qq * 16 + g * 4 + r;
            if (qrow < N_Q) {
                atomicAdd(&out[(size_t)qrow * 128 + n0 * 16 + c],        v0[r]);
                atomicAdd(&out[(size_t)qrow * 128 + (n0 + 1) * 16 + c],  v1[r]);
            }
        }
    }
}

// ================= fallback: round-1 fused kernel (used if ws too small) =================
__global__ __launch_bounds__(256, 2) void k_main_fb(
    const float* __restrict__ qp, const float* __restrict__ sp,
    const int* __restrict__ nb, const float* __restrict__ kp,
    const ushortT* __restrict__ xbf, const ushortT* __restrict__ wfrag,
    float* __restrict__ out)
{
    __shared__ ushortT s_w[16][32][16];
    __shared__ int s_idx[16][32];
    __shared__ __align__(16) ushortT s_wf[16][1928];

    const int t   = threadIdx.x;
    const int blk = blockIdx.x;

    {
        const int q  = t >> 4;
        const int h0 = t & 15;
        const int qg = blk * 16 + q;
        const int qc = (qg < N_Q) ? qg : 0;
        const float qx = qp[qc * 3 + 0], qy = qp[qc * 3 + 1], qz = qp[qc * 3 + 2];
        #pragma unroll
        for (int i = 0; i < 2; ++i) {
            const int h  = h0 + 16 * i;
            int idx = (qg < N_Q) ? nb[qg * 32 + h] : M_S;
            const bool valid = ((unsigned)idx < (unsigned)M_S);
            s_idx[q][h] = valid ? idx : 0;
            float px, py, pz;
            if (valid) { px = sp[idx * 3]; py = sp[idx * 3 + 1]; pz = sp[idx * 3 + 2]; }
            else       { px = 1e6f; py = 1e6f; pz = 1e6f; }
            const float rx = px - qx, ry = py - qy, rz = pz - qz;
            #pragma unroll
            for (int k = 0; k < 15; ++k) {
                const float dx = rx - kp[k * 3 + 0];
                const float dy = ry - kp[k * 3 + 1];
                const float dz = rz - kp[k * 3 + 2];
                const float d2 = dx * dx + dy * dy + dz * dz;
                float wv = 1.0f - sqrtf(d2) * (1.0f / 1.2f);
                wv = (wv > 0.0f) ? wv : 0.0f;
                s_w[q][h][k] = f2b(wv);
            }
            s_w[q][h][15] = 0;
        }
    }
    __syncthreads();

    {
        const int q  = t >> 4;
        const int c0 = (t & 15) * 8;
        float acc[15][8];
        #pragma unroll
        for (int k = 0; k < 15; ++k)
            #pragma unroll
            for (int j = 0; j < 8; ++j) acc[k][j] = 0.0f;

        int idx0 = s_idx[q][0];
        us8 xv = *(const us8*)(xbf + (size_t)idx0 * C_INV + c0);
        for (int h = 0; h < 32; ++h) {
            const us8 xc = xv;
            if (h < 31) {
                int idn = s_idx[q][h + 1];
                xv = *(const us8*)(xbf + (size_t)idn * C_INV + c0);
            }
            const us8 w0 = *(const us8*)&s_w[q][h][0];
            const us8 w1 = *(const us8*)&s_w[q][h][8];
            float xf[8];
            #pragma unroll
            for (int j = 0; j < 8; ++j) xf[j] = b2f(xc[j]);
            #pragma unroll
            for (int k = 0; k < 15; ++k) {
                const float wk = b2f((k < 8) ? w0[k] : w1[k - 8]);
                #pragma unroll
                for (int j = 0; j < 8; ++j) acc[k][j] += wk * xf[j];
            }
        }
        #pragma unroll
        for (int k = 0; k < 15; ++k) {
            us8 o;
            #pragma unroll
            for (int j = 0; j < 8; ++j) o[j] = f2b(acc[k][j]);
            *(us8*)&s_wf[q][k * C_INV + c0] = o;
        }
    }
    __syncthreads();

    {
        const int lane = t & 63;
        const int wv   = t >> 6;
        const int db0  = wv * 2;
        const int arow = lane & 15;
        const int kofs = (lane >> 4) * 8;
        f32x4 acc0 = {0.f, 0.f, 0.f, 0.f};
        f32x4 acc1 = {0.f, 0.f, 0.f, 0.f};
        #pragma unroll 4
        for (int ks = 0; ks < 60; ++ks) {
            s8v a  = *(const s8v*)&s_wf[arow][ks * 32 + kofs];
            s8v b0 = *(const s8v*)(wfrag + ((size_t)(ks * 8 + db0) * 64 + lane) * 8);
            s8v b1 = *(const s8v*)(wfrag + ((size_t)(ks * 8 + db0 + 1) * 64 + lane) * 8);
            acc0 = __builtin_amdgcn_mfma_f32_16x16x32_bf16(a, b0, acc0, 0, 0, 0);
            acc1 = __builtin_amdgcn_mfma_f32_16x16x32_bf16(a, b1, acc1, 0, 0, 0);
        }
        #pragma unroll
        for (int r = 0; r < 4; ++r) {
            const int q  = (lane >> 4) * 4 + r;
            const int qg = blk * 16 + q;
            if (qg < N_Q) {
                out[(size_t)qg * 128 + db0 * 16 + (lane & 15)]       = acc0[r];
                out[(size_t)qg * 128 + (db0 + 1) * 16 + (lane & 15)] = acc1[r];
            }
        }
    }
}

extern "C" void kernel_launch(void* const* d_in, const int* in_sizes, int n_in,
                              void* d_out, int out_size, void* d_ws, size_t ws_size,
                              hipStream_t stream) {
    const float* x  = (const float*)d_in[0];
    const float* qp = (const float*)d_in[1];
    const float* sp = (const float*)d_in[2];
    const int*   nb = (const int*)d_in[3];
    const float* kp = (const float*)d_in[4];
    const float* W  = (const float*)d_in[5];
    float* out = (float*)d_out;

    const size_t xbf_b   = (size_t)M_S * C_INV * 2;        // 6,400,000
    const size_t wfrag_b = (size_t)2048 * 128 * 2;         // 524,288
    const size_t wf_b    = (size_t)25024 * 2048 * 2;       // 102,498,304

    ushortT* xbf   = (ushortT*)d_ws;
    ushortT* wfrag = (ushortT*)((char*)d_ws + xbf_b);
    ushortT* wfbuf = (ushortT*)((char*)d_ws + xbf_b + wfrag_b);

    k_convert_x<<<3125, 256, 0, stream>>>(x, xbf);

    if (ws_size >= xbf_b + wfrag_b + wf_b) {
        k_build_wfrag2<<<1024, 256, 0, stream>>>(W, wfrag);
        k_zero<<<3125, 256, 0, stream>>>(out);
        k_ab<<<3125, 256, 0, stream>>>(qp, sp, nb, kp, xbf, wfbuf);
        k_gemm<<<391 * 4, 256, 0, stream>>>(wfbuf, wfrag, out);
    } else {
        k_build_wfrag<<<960, 256, 0, stream>>>(W, wfrag);
        k_main_fb<<<(N_Q + 15) / 16, 256, 0, stream>>>(qp, sp, nb, kp, xbf, wfrag, out);
    }
}

// Round 10
// 109.004 us; speedup vs baseline: 1.4052x; 1.4052x over previous
//
#include <hip/hip_runtime.h>
#include <hip/hip_bf16.h>

#define N_Q   25000
#define M_S   25000
#define C_INV 128

typedef unsigned short ushortT;
typedef unsigned short us8 __attribute__((ext_vector_type(8)));
typedef unsigned short us4 __attribute__((ext_vector_type(4)));
typedef short s8v __attribute__((ext_vector_type(8)));
typedef float f32x4 __attribute__((ext_vector_type(4)));

__device__ __forceinline__ float b2f(ushortT u) {
    unsigned v = ((unsigned)u) << 16;
    return __builtin_bit_cast(float, v);
}
__device__ __forceinline__ ushortT f2b(float f) {
    __hip_bfloat16 h = __float2bfloat16(f);
    return __builtin_bit_cast(ushortT, h);
}

// ---------------- kernel 1: x fp32 -> bf16 ----------------
__global__ void k_convert_x(const float* __restrict__ x, ushortT* __restrict__ xb) {
    int i = blockIdx.x * 256 + threadIdx.x;
    const int n4 = (M_S * C_INV) / 4;
    if (i >= n4) return;
    float4 v = ((const float4*)x)[i];
    us4 o;
    o[0] = f2b(v.x); o[1] = f2b(v.y); o[2] = f2b(v.z); o[3] = f2b(v.w);
    ((us4*)xb)[i] = o;
}

// ---------------- kernel 2: W fp32 -> permuted-K fragment-major bf16 (K padded 2048) ----------------
// p = ci*256 + ls*4 + r  ->  (k = (ls>>4)*4 + r, c = ci*16 + (ls&15)), zero for k==15.
// wfrag elem o = ((ks*8 + db)*64 + lane)*8 + j holds W_perm[ks*32 + (lane>>4)*8 + j][db*16 + (lane&15)].
__global__ void k_build_wfrag2(const float* __restrict__ W, ushortT* __restrict__ wf) {
    int o = blockIdx.x * 256 + threadIdx.x;
    if (o >= 262144) return;                 // 2048 * 128
    int j   = o & 7;
    int l   = (o >> 3) & 63;
    int db  = (o >> 9) & 7;
    int ks  = o >> 12;                       // 0..63
    int p   = ks * 32 + ((l >> 4) * 8) + j;  // 0..2047
    int ci  = p >> 8;
    int rem = p & 255;
    int ls  = rem >> 2;
    int r   = rem & 3;
    int k   = (ls >> 4) * 4 + r;
    int c   = ci * 16 + (ls & 15);
    int d   = db * 16 + (l & 15);
    wf[o] = (k < 15) ? f2b(W[((size_t)k * 128 + c) * 128 + d]) : (ushortT)0;
}

// ================= fused kernel: Q-tile 16, 1024 threads, 80 KB LDS, 2 blocks/CU =================
// LDS carve (r8/r9 crash root-cause: s_w is 16 KB, was given only 8 KB -> OOB writes):
//   s_wf 65536 B + s_w 16384 B = 81920 B exactly (2 x 80 KB = 160 KB/CU).
// s_idx eliminated: Phase A assigns q = wave, so lane 2h of wave w holds idx(q=w, h);
// Phase B fetches the 8 needed indices via intra-wave __shfl.
__global__ __launch_bounds__(1024, 8) void k_fused16(
    const float* __restrict__ qp, const float* __restrict__ sp,
    const int* __restrict__ nb, const float* __restrict__ kp,
    const ushortT* __restrict__ xbf, const ushortT* __restrict__ wfrag,
    float* __restrict__ out)
{
    __shared__ __align__(16) char smem[81920];
    ushortT* s_w   = (ushortT*)(smem + 65536);   // [16 q][(h>>3)*128 + k*8 + (h&7)]  16384 B
    float*   s_out = (float*)(smem + 65536);     // 8192 B, aliases s_w (dead in phase C)

    const int t   = threadIdx.x;
    const int l   = t & 63;
    const int w   = t >> 6;          // wave 0..15 == q
    const int blk = blockIdx.x;

    // ---- Phase A: wave w owns q=w; lane l = (h = l>>1, kh = l&1) ----
    int idc;   // this lane's clamped neighbor row
    {
        const int q  = w;
        const int h  = l >> 1;
        const int kh = l & 1;
        const int qg = blk * 16 + q;
        const int qc = (qg < N_Q) ? qg : (N_Q - 1);
        const float qx = qp[qc * 3 + 0], qy = qp[qc * 3 + 1], qz = qp[qc * 3 + 2];
        int idx = (qg < N_Q) ? nb[qg * 32 + h] : M_S;
        const bool valid = ((unsigned)idx < (unsigned)M_S);
        idc = valid ? idx : 0;
        float px, py, pz;
        if (valid) { px = sp[idc * 3]; py = sp[idc * 3 + 1]; pz = sp[idc * 3 + 2]; }
        else       { px = 1e6f; py = 1e6f; pz = 1e6f; }
        const float rx = px - qx, ry = py - qy, rz = pz - qz;
        #pragma unroll
        for (int kk = 0; kk < 8; ++kk) {
            const int k = kh * 8 + kk;
            float wv = 0.0f;
            if (k < 15) {
                const float dx = rx - kp[k * 3 + 0];
                const float dy = ry - kp[k * 3 + 1];
                const float dz = rz - kp[k * 3 + 2];
                const float d2 = dx * dx + dy * dy + dz * dz;
                wv = 1.0f - sqrtf(d2) * (1.0f / 1.2f);
                wv = (wv > 0.0f) ? wv : 0.0f;
            }
            s_w[q * 512 + (h >> 3) * 128 + k * 8 + (h & 7)] = f2b(wv);
        }
    }
    __syncthreads();

    // ---- Phase B: wave w computes wf row q=w; register gather + MFMA;
    //      XOR-swizzled us4 LDS store into s_wf [r4-verified expressions] ----
    {
        const int q  = w;
        const int g  = l >> 4;
        const int c0 = l & 15;
        const s8v af = *(const s8v*)(s_w + q * 512 + g * 128 + c0 * 8);

        // 8 neighbor rows for h = g*8 + j live in lanes g*16 + 2j of this wave
        const int r0 = __shfl(idc, g * 16 + 0,  64);
        const int r1 = __shfl(idc, g * 16 + 2,  64);
        const int r2 = __shfl(idc, g * 16 + 4,  64);
        const int r3 = __shfl(idc, g * 16 + 6,  64);
        const int r4 = __shfl(idc, g * 16 + 8,  64);
        const int r5 = __shfl(idc, g * 16 + 10, 64);
        const int r6 = __shfl(idc, g * 16 + 12, 64);
        const int r7 = __shfl(idc, g * 16 + 14, 64);
        const ushortT* bp = xbf + c0;

        #pragma unroll
        for (int cg = 0; cg < 2; ++cg) {
            us8 xr0, xr1, xr2, xr3;   // xr[u][j] = x[row j][(cg*4+u)*16 + c0]
            #pragma unroll
            for (int u = 0; u < 4; ++u) {
                const int ofs = (cg * 4 + u) * 16;
                us8 v;
                v[0] = bp[(size_t)r0 * 128 + ofs];
                v[1] = bp[(size_t)r1 * 128 + ofs];
                v[2] = bp[(size_t)r2 * 128 + ofs];
                v[3] = bp[(size_t)r3 * 128 + ofs];
                v[4] = bp[(size_t)r4 * 128 + ofs];
                v[5] = bp[(size_t)r5 * 128 + ofs];
                v[6] = bp[(size_t)r6 * 128 + ofs];
                v[7] = bp[(size_t)r7 * 128 + ofs];
                if (u == 0) xr0 = v; else if (u == 1) xr1 = v; else if (u == 2) xr2 = v; else xr3 = v;
            }
            #pragma unroll
            for (int u = 0; u < 4; ++u) {
                const int ci = cg * 4 + u;
                const us8 xv = (u == 0) ? xr0 : (u == 1) ? xr1 : (u == 2) ? xr2 : xr3;
                f32x4 d = __builtin_amdgcn_mfma_f32_16x16x32_bf16(
                    af, __builtin_bit_cast(s8v, xv), (f32x4){0.f, 0.f, 0.f, 0.f}, 0, 0, 0);
                us4 o4;
                o4[0] = f2b(d[0]); o4[1] = f2b(d[1]); o4[2] = f2b(d[2]); o4[3] = f2b(d[3]);
                const unsigned byteoff = (unsigned)q * 4096u
                                       + ((((unsigned)ci * 512u) + ((unsigned)l * 8u)) ^ (((unsigned)q & 7u) << 4));
                *(us4*)(smem + byteoff) = o4;
            }
        }
    }
    __syncthreads();   // s_wf complete; s_w dead

    // ---- zero s_out (aliases s_w) ----
    ((float2*)s_out)[t] = float2{0.f, 0.f};
    __syncthreads();

    // ---- Phase C: out[16 q][128 d] = s_wf[16][2048] @ W_perm[2048][128]
    //      wave (ko = w>>3, n = w&7): every W-fragment read exactly once ----
    {
        const int ko = w >> 3;
        const int n  = w & 7;
        f32x4 acc = {0.f, 0.f, 0.f, 0.f};
        #pragma unroll 4
        for (int tt = 0; tt < 32; ++tt) {
            const int ks = tt * 2 + ko;
            const s8v b = *(const s8v*)(wfrag + ((size_t)(ks * 8 + n) * 64 + l) * 8);
            const unsigned inner = (((unsigned)ks * 64u) + (((unsigned)(l >> 4)) * 16u))
                                 ^ ((((unsigned)l & 7u)) << 4);
            const s8v a = *(const s8v*)(smem + (unsigned)(l & 15) * 4096u + inner);
            acc = __builtin_amdgcn_mfma_f32_16x16x32_bf16(a, b, acc, 0, 0, 0);
        }
        #pragma unroll
        for (int r = 0; r < 4; ++r) {
            const int row = (l >> 4) * 4 + r;
            atomicAdd(&s_out[row * 128 + n * 16 + (l & 15)], acc[r]);
        }
    }
    __syncthreads();

    // ---- write out ----
    if (t < 512) {
        const int q  = t >> 5;
        const int i  = t & 31;
        const int qg = blk * 16 + q;
        if (qg < N_Q)
            ((float4*)(out + (size_t)qg * 128))[i] = ((const float4*)s_out)[q * 32 + i];
    }
}

extern "C" void kernel_launch(void* const* d_in, const int* in_sizes, int n_in,
                              void* d_out, int out_size, void* d_ws, size_t ws_size,
                              hipStream_t stream) {
    const float* x  = (const float*)d_in[0];
    const float* qp = (const float*)d_in[1];
    const float* sp = (const float*)d_in[2];
    const int*   nb = (const int*)d_in[3];
    const float* kp = (const float*)d_in[4];
    const float* W  = (const float*)d_in[5];
    float* out = (float*)d_out;

    const size_t xbf_b = (size_t)M_S * C_INV * 2;          // 6,400,000
    ushortT* xbf   = (ushortT*)d_ws;
    ushortT* wfrag = (ushortT*)((char*)d_ws + xbf_b);      // 524,288

    k_convert_x<<<3125, 256, 0, stream>>>(x, xbf);
    k_build_wfrag2<<<1024, 256, 0, stream>>>(W, wfrag);

    const int nblk = (N_Q + 15) / 16;   // 1563
    k_fused16<<<nblk, 1024, 0, stream>>>(qp, sp, nb, kp, xbf, wfrag, out);
}

// Round 11
// 90.361 us; speedup vs baseline: 1.6952x; 1.2063x over previous
//
#include <hip/hip_runtime.h>
#include <hip/hip_bf16.h>

#define N_Q   25000
#define M_S   25000
#define C_INV 128

typedef unsigned short ushortT;
typedef unsigned short us8 __attribute__((ext_vector_type(8)));
typedef unsigned short us4 __attribute__((ext_vector_type(4)));
typedef short s8v __attribute__((ext_vector_type(8)));
typedef float f32x4 __attribute__((ext_vector_type(4)));

#define GAS __attribute__((address_space(1)))
#define LAS __attribute__((address_space(3)))

__device__ __forceinline__ float b2f(ushortT u) {
    unsigned v = ((unsigned)u) << 16;
    return __builtin_bit_cast(float, v);
}
__device__ __forceinline__ ushortT f2b(float f) {
    __hip_bfloat16 h = __float2bfloat16(f);
    return __builtin_bit_cast(ushortT, h);
}

// ---------------- kernel 1: x fp32 -> bf16 ----------------
__global__ void k_convert_x(const float* __restrict__ x, ushortT* __restrict__ xb) {
    int i = blockIdx.x * 256 + threadIdx.x;
    const int n4 = (M_S * C_INV) / 4;
    if (i >= n4) return;
    float4 v = ((const float4*)x)[i];
    us4 o;
    o[0] = f2b(v.x); o[1] = f2b(v.y); o[2] = f2b(v.z); o[3] = f2b(v.w);
    ((us4*)xb)[i] = o;
}

// ---------------- kernel 2: W fp32 -> permuted-K fragment-major bf16 (K padded 2048) ----------------
__global__ void k_build_wfrag2(const float* __restrict__ W, ushortT* __restrict__ wf) {
    int o = blockIdx.x * 256 + threadIdx.x;
    if (o >= 262144) return;                 // 2048 * 128
    int j   = o & 7;
    int l   = (o >> 3) & 63;
    int db  = (o >> 9) & 7;
    int ks  = o >> 12;                       // 0..63
    int p   = ks * 32 + ((l >> 4) * 8) + j;  // 0..2047
    int ci  = p >> 8;
    int rem = p & 255;
    int ls  = rem >> 2;
    int r   = rem & 3;
    int k   = (ls >> 4) * 4 + r;
    int c   = ci * 16 + (ls & 15);
    int d   = db * 16 + (l & 15);
    wf[o] = (k < 15) ? f2b(W[((size_t)k * 128 + c) * 128 + d]) : (ushortT)0;
}

// ---------------- kernel 2b: old wfrag layout (fallback path only) ----------------
__global__ void k_build_wfrag(const float* __restrict__ W, ushortT* __restrict__ wf) {
    int o = blockIdx.x * 256 + threadIdx.x;
    if (o >= 1920 * 128) return;
    int j  = o & 7;
    int l  = (o >> 3) & 63;
    int db = (o >> 9) & 7;
    int ks = o >> 12;
    int r  = ks * 32 + ((l >> 4) * 8) + j;
    int d  = db * 16 + (l & 15);
    wf[o] = f2b(W[r * 128 + d]);
}

// ================= K1 (r5-verified): stages A+B, register gather, fragment-major wf =================
__global__ __launch_bounds__(512, 4) void k_ab(
    const float* __restrict__ qp, const float* __restrict__ sp,
    const int* __restrict__ nb, const float* __restrict__ kp,
    const ushortT* __restrict__ xbf, ushortT* __restrict__ wf_out)
{
    __shared__ __align__(16) ushortT s_w[16 * 512];   // 16 KB fragment layout [q][(h>>3)*128 + k*8 + (h&7)]
    __shared__ int s_idx[16 * 32];                    //  2 KB

    const int t   = threadIdx.x;
    const int l   = t & 63;
    const int w   = t >> 6;          // wave 0..7
    const int blk = blockIdx.x;

    // ---- Phase A ----
    {
        const int q  = t >> 5;
        const int h  = t & 31;
        const int qg = blk * 16 + q;
        const int qc = (qg < N_Q) ? qg : (N_Q - 1);
        const float qx = qp[qc * 3 + 0], qy = qp[qc * 3 + 1], qz = qp[qc * 3 + 2];
        int idx = (qg < N_Q) ? nb[qg * 32 + h] : M_S;
        const bool valid = ((unsigned)idx < (unsigned)M_S);
        const int idc = valid ? idx : 0;
        s_idx[q * 32 + h] = idc;
        float px, py, pz;
        if (valid) { px = sp[idc * 3]; py = sp[idc * 3 + 1]; pz = sp[idc * 3 + 2]; }
        else       { px = 1e6f; py = 1e6f; pz = 1e6f; }
        const float rx = px - qx, ry = py - qy, rz = pz - qz;
        #pragma unroll
        for (int k = 0; k < 15; ++k) {
            const float dx = rx - kp[k * 3 + 0];
            const float dy = ry - kp[k * 3 + 1];
            const float dz = rz - kp[k * 3 + 2];
            const float d2 = dx * dx + dy * dy + dz * dz;
            float wv = 1.0f - sqrtf(d2) * (1.0f / 1.2f);
            wv = (wv > 0.0f) ? wv : 0.0f;
            s_w[q * 512 + (h >> 3) * 128 + k * 8 + (h & 7)] = f2b(wv);
        }
        s_w[q * 512 + (h >> 3) * 128 + 15 * 8 + (h & 7)] = 0;
    }
    __syncthreads();

    const int c0 = l & 15;
    const int hg = l >> 4;

    s8v af[2];
    int ridx[2][8];
    #pragma unroll
    for (int qi = 0; qi < 2; ++qi) {
        const int q = w * 2 + qi;
        af[qi] = *(const s8v*)(s_w + q * 512 + hg * 128 + c0 * 8);
        #pragma unroll
        for (int j = 0; j < 8; ++j)
            ridx[qi][j] = s_idx[q * 32 + hg * 8 + j];
    }

    us4* wfo = (us4*)wf_out;

    #pragma unroll
    for (int qi = 0; qi < 2; ++qi) {
        const int qrow = blk * 16 + w * 2 + qi;
        const ushortT* rp[8];
        #pragma unroll
        for (int j = 0; j < 8; ++j)
            rp[j] = xbf + (size_t)ridx[qi][j] * 128 + c0;

        us8 xr[8];   // xr[ci][j] = x[idx[hg*8+j]][ci*16 + c0]
        #pragma unroll
        for (int j = 0; j < 8; ++j) {
            #pragma unroll
            for (int ci = 0; ci < 8; ++ci)
                xr[ci][j] = rp[j][ci * 16];
        }
        #pragma unroll
        for (int ci = 0; ci < 8; ++ci) {
            f32x4 d = __builtin_amdgcn_mfma_f32_16x16x32_bf16(
                af[qi], __builtin_bit_cast(s8v, xr[ci]), (f32x4){0.f, 0.f, 0.f, 0.f}, 0, 0, 0);
            us4 o;
            o[0] = f2b(d[0]); o[1] = f2b(d[1]); o[2] = f2b(d[2]); o[3] = f2b(d[3]);
            wfo[(size_t)qrow * 512 + ci * 64 + l] = o;
        }
    }
}

// ================= K2 v8: K-split-2 GEMM; slice 0 -> out, slice 1 -> p1 =================
__global__ __launch_bounds__(512, 4) void k_gemm_split(
    const ushortT* __restrict__ wf, const ushortT* __restrict__ wfrag,
    float* __restrict__ out, float* __restrict__ p1)
{
    __shared__ __align__(16) ushortT sA[2][8192];

    const int t    = threadIdx.x;
    const int l    = t & 63;
    const int w    = t >> 6;          // 0..7
    const int blk  = blockIdx.x;
    const int tile = blk >> 1;        // 0..390
    const int ksl  = blk & 1;         // K half
    const int qg   = w >> 2;          // 0..1
    const int n0   = (w & 3) * 2;     // 0,2,4,6

    auto stage = [&](int c4, int buf) {
        #pragma unroll
        for (int u = 0; u < 2; ++u) {
            const int s    = u * 512 + t;
            const int q    = s >> 4;
            const int part = s & 15;
            const ushortT* src = wf + (size_t)(tile * 64 + q) * 2048 + c4 * 128
                               + ((part ^ (q & 7)) * 8);
            __builtin_amdgcn_global_load_lds((const GAS unsigned int*)(const void*)src,
                                             (LAS unsigned int*)(void*)(&sA[buf][(size_t)s * 8]),
                                             16, 0, 0);
        }
    };

    f32x4 a00 = {0.f,0.f,0.f,0.f}, a01 = {0.f,0.f,0.f,0.f};
    f32x4 a10 = {0.f,0.f,0.f,0.f}, a11 = {0.f,0.f,0.f,0.f};

    const int c4beg = ksl * 8;
    stage(c4beg, 0);
    __syncthreads();

    for (int c4 = c4beg; c4 < c4beg + 8; ++c4) {
        if (c4 < c4beg + 7) stage(c4 + 1, (c4 + 1) & 1);
        const ushortT* A = sA[c4 & 1];
        const int q0 = qg * 32 + (l & 15);
        const int q1 = q0 + 16;
        #pragma unroll
        for (int kk = 0; kk < 4; ++kk) {
            const int ks = c4 * 4 + kk;
            const s8v b0 = *(const s8v*)(wfrag + ((size_t)(ks * 8 + n0    ) * 64 + l) * 8);
            const s8v b1 = *(const s8v*)(wfrag + ((size_t)(ks * 8 + n0 + 1) * 64 + l) * 8);
            const int eo = kk * 32 + (l >> 4) * 8;
            const s8v av0 = *(const s8v*)(A + q0 * 128 + (eo ^ ((q0 & 7) * 8)));
            const s8v av1 = *(const s8v*)(A + q1 * 128 + (eo ^ ((q1 & 7) * 8)));
            a00 = __builtin_amdgcn_mfma_f32_16x16x32_bf16(av0, b0, a00, 0, 0, 0);
            a01 = __builtin_amdgcn_mfma_f32_16x16x32_bf16(av0, b1, a01, 0, 0, 0);
            a10 = __builtin_amdgcn_mfma_f32_16x16x32_bf16(av1, b0, a10, 0, 0, 0);
            a11 = __builtin_amdgcn_mfma_f32_16x16x32_bf16(av1, b1, a11, 0, 0, 0);
        }
        __syncthreads();
    }

    float* dst = ksl ? p1 : out;
    #pragma unroll
    for (int r = 0; r < 4; ++r) {
        const int qa = tile * 64 + qg * 32 + (l >> 4) * 4 + r;
        const int qb = qa + 16;
        const int d0 = n0 * 16 + (l & 15);
        if (qa < N_Q) {
            dst[(size_t)qa * 128 + d0]      = a00[r];
            dst[(size_t)qa * 128 + d0 + 16] = a01[r];
        }
        if (qb < N_Q) {
            dst[(size_t)qb * 128 + d0]      = a10[r];
            dst[(size_t)qb * 128 + d0 + 16] = a11[r];
        }
    }
}

// ---------------- reduce: out += p1 ----------------
__global__ void k_reduce(float* __restrict__ out, const float* __restrict__ p1) {
    int i = blockIdx.x * 256 + threadIdx.x;
    if (i >= (N_Q * 128) / 4) return;
    float4 a = ((const float4*)out)[i];
    float4 b = ((const float4*)p1)[i];
    a.x += b.x; a.y += b.y; a.z += b.z; a.w += b.w;
    ((float4*)out)[i] = a;
}

// ================= K2 (r5-verified, full-K): used when ws fits split buffers but not p1 =================
__global__ __launch_bounds__(512, 4) void k_gemm_full(
    const ushortT* __restrict__ wf, const ushortT* __restrict__ wfrag,
    float* __restrict__ out)
{
    __shared__ __align__(16) ushortT sA[2][8192];

    const int t   = threadIdx.x;
    const int l   = t & 63;
    const int w   = t >> 6;
    const int blk = blockIdx.x;
    const int qg  = w >> 2;
    const int n0  = (w & 3) * 2;

    auto stage = [&](int c4, int buf) {
        #pragma unroll
        for (int u = 0; u < 2; ++u) {
            const int s    = u * 512 + t;
            const int q    = s >> 4;
            const int part = s & 15;
            const ushortT* src = wf + (size_t)(blk * 64 + q) * 2048 + c4 * 128
                               + ((part ^ (q & 7)) * 8);
            __builtin_amdgcn_global_load_lds((const GAS unsigned int*)(const void*)src,
                                             (LAS unsigned int*)(void*)(&sA[buf][(size_t)s * 8]),
                                             16, 0, 0);
        }
    };

    f32x4 a00 = {0.f,0.f,0.f,0.f}, a01 = {0.f,0.f,0.f,0.f};
    f32x4 a10 = {0.f,0.f,0.f,0.f}, a11 = {0.f,0.f,0.f,0.f};

    stage(0, 0);
    __syncthreads();

    for (int c4 = 0; c4 < 16; ++c4) {
        if (c4 < 15) stage(c4 + 1, (c4 + 1) & 1);
        const ushortT* A = sA[c4 & 1];
        const int q0 = qg * 32 + (l & 15);
        const int q1 = q0 + 16;
        #pragma unroll
        for (int kk = 0; kk < 4; ++kk) {
            const int ks = c4 * 4 + kk;
            const s8v b0 = *(const s8v*)(wfrag + ((size_t)(ks * 8 + n0    ) * 64 + l) * 8);
            const s8v b1 = *(const s8v*)(wfrag + ((size_t)(ks * 8 + n0 + 1) * 64 + l) * 8);
            const int eo = kk * 32 + (l >> 4) * 8;
            const s8v av0 = *(const s8v*)(A + q0 * 128 + (eo ^ ((q0 & 7) * 8)));
            const s8v av1 = *(const s8v*)(A + q1 * 128 + (eo ^ ((q1 & 7) * 8)));
            a00 = __builtin_amdgcn_mfma_f32_16x16x32_bf16(av0, b0, a00, 0, 0, 0);
            a01 = __builtin_amdgcn_mfma_f32_16x16x32_bf16(av0, b1, a01, 0, 0, 0);
            a10 = __builtin_amdgcn_mfma_f32_16x16x32_bf16(av1, b0, a10, 0, 0, 0);
            a11 = __builtin_amdgcn_mfma_f32_16x16x32_bf16(av1, b1, a11, 0, 0, 0);
        }
        __syncthreads();
    }

    #pragma unroll
    for (int r = 0; r < 4; ++r) {
        const int qa = blk * 64 + qg * 32 + (l >> 4) * 4 + r;
        const int qb = qa + 16;
        const int d0 = n0 * 16 + (l & 15);
        if (qa < N_Q) {
            out[(size_t)qa * 128 + d0]      = a00[r];
            out[(size_t)qa * 128 + d0 + 16] = a01[r];
        }
        if (qb < N_Q) {
            out[(size_t)qb * 128 + d0]      = a10[r];
            out[(size_t)qb * 128 + d0 + 16] = a11[r];
        }
    }
}

// ================= fallback: round-1 fused kernel (tiny ws) =================
__global__ __launch_bounds__(256, 2) void k_main_fb(
    const float* __restrict__ qp, const float* __restrict__ sp,
    const int* __restrict__ nb, const float* __restrict__ kp,
    const ushortT* __restrict__ xbf, const ushortT* __restrict__ wfrag,
    float* __restrict__ out)
{
    __shared__ ushortT s_w[16][32][16];
    __shared__ int s_idx[16][32];
    __shared__ __align__(16) ushortT s_wf[16][1928];

    const int t   = threadIdx.x;
    const int blk = blockIdx.x;

    {
        const int q  = t >> 4;
        const int h0 = t & 15;
        const int qg = blk * 16 + q;
        const int qc = (qg < N_Q) ? qg : 0;
        const float qx = qp[qc * 3 + 0], qy = qp[qc * 3 + 1], qz = qp[qc * 3 + 2];
        #pragma unroll
        for (int i = 0; i < 2; ++i) {
            const int h  = h0 + 16 * i;
            int idx = (qg < N_Q) ? nb[qg * 32 + h] : M_S;
            const bool valid = ((unsigned)idx < (unsigned)M_S);
            s_idx[q][h] = valid ? idx : 0;
            float px, py, pz;
            if (valid) { px = sp[idx * 3]; py = sp[idx * 3 + 1]; pz = sp[idx * 3 + 2]; }
            else       { px = 1e6f; py = 1e6f; pz = 1e6f; }
            const float rx = px - qx, ry = py - qy, rz = pz - qz;
            #pragma unroll
            for (int k = 0; k < 15; ++k) {
                const float dx = rx - kp[k * 3 + 0];
                const float dy = ry - kp[k * 3 + 1];
                const float dz = rz - kp[k * 3 + 2];
                const float d2 = dx * dx + dy * dy + dz * dz;
                float wv = 1.0f - sqrtf(d2) * (1.0f / 1.2f);
                wv = (wv > 0.0f) ? wv : 0.0f;
                s_w[q][h][k] = f2b(wv);
            }
            s_w[q][h][15] = 0;
        }
    }
    __syncthreads();

    {
        const int q  = t >> 4;
        const int c0 = (t & 15) * 8;
        float acc[15][8];
        #pragma unroll
        for (int k = 0; k < 15; ++k)
            #pragma unroll
            for (int j = 0; j < 8; ++j) acc[k][j] = 0.0f;

        int idx0 = s_idx[q][0];
        us8 xv = *(const us8*)(xbf + (size_t)idx0 * C_INV + c0);
        for (int h = 0; h < 32; ++h) {
            const us8 xc = xv;
            if (h < 31) {
                int idn = s_idx[q][h + 1];
                xv = *(const us8*)(xbf + (size_t)idn * C_INV + c0);
            }
            const us8 w0 = *(const us8*)&s_w[q][h][0];
            const us8 w1 = *(const us8*)&s_w[q][h][8];
            float xf[8];
            #pragma unroll
            for (int j = 0; j < 8; ++j) xf[j] = b2f(xc[j]);
            #pragma unroll
            for (int k = 0; k < 15; ++k) {
                const float wk = b2f((k < 8) ? w0[k] : w1[k - 8]);
                #pragma unroll
                for (int j = 0; j < 8; ++j) acc[k][j] += wk * xf[j];
            }
        }
        #pragma unroll
        for (int k = 0; k < 15; ++k) {
            us8 o;
            #pragma unroll
            for (int j = 0; j < 8; ++j) o[j] = f2b(acc[k][j]);
            *(us8*)&s_wf[q][k * C_INV + c0] = o;
        }
    }
    __syncthreads();

    {
        const int lane = t & 63;
        const int wv   = t >> 6;
        const int db0  = wv * 2;
        const int arow = lane & 15;
        const int kofs = (lane >> 4) * 8;
        f32x4 acc0 = {0.f, 0.f, 0.f, 0.f};
        f32x4 acc1 = {0.f, 0.f, 0.f, 0.f};
        #pragma unroll 4
        for (int ks = 0; ks < 60; ++ks) {
            s8v a  = *(const s8v*)&s_wf[arow][ks * 32 + kofs];
            s8v b0 = *(const s8v*)(wfrag + ((size_t)(ks * 8 + db0) * 64 + lane) * 8);
            s8v b1 = *(const s8v*)(wfrag + ((size_t)(ks * 8 + db0 + 1) * 64 + lane) * 8);
            acc0 = __builtin_amdgcn_mfma_f32_16x16x32_bf16(a, b0, acc0, 0, 0, 0);
            acc1 = __builtin_amdgcn_mfma_f32_16x16x32_bf16(a, b1, acc1, 0, 0, 0);
        }
        #pragma unroll
        for (int r = 0; r < 4; ++r) {
            const int q  = (lane >> 4) * 4 + r;
            const int qg = blk * 16 + q;
            if (qg < N_Q) {
                out[(size_t)qg * 128 + db0 * 16 + (lane & 15)]       = acc0[r];
                out[(size_t)qg * 128 + (db0 + 1) * 16 + (lane & 15)] = acc1[r];
            }
        }
    }
}

extern "C" void kernel_launch(void* const* d_in, const int* in_sizes, int n_in,
                              void* d_out, int out_size, void* d_ws, size_t ws_size,
                              hipStream_t stream) {
    const float* x  = (const float*)d_in[0];
    const float* qp = (const float*)d_in[1];
    const float* sp = (const float*)d_in[2];
    const int*   nb = (const int*)d_in[3];
    const float* kp = (const float*)d_in[4];
    const float* W  = (const float*)d_in[5];
    float* out = (float*)d_out;

    const size_t xbf_b   = (size_t)M_S * C_INV * 2;        // 6,400,000
    const size_t wfrag_b = (size_t)2048 * 128 * 2;         // 524,288
    const size_t wf_b    = (size_t)25024 * 2048 * 2;       // 102,498,304
    const size_t p1_b    = (size_t)25024 * 128 * 4;        // 12,812,288

    ushortT* xbf   = (ushortT*)d_ws;
    ushortT* wfrag = (ushortT*)((char*)d_ws + xbf_b);
    ushortT* wfbuf = (ushortT*)((char*)d_ws + xbf_b + wfrag_b);
    float*   p1    = (float*)((char*)d_ws + xbf_b + wfrag_b + wf_b);

    k_convert_x<<<3125, 256, 0, stream>>>(x, xbf);

    if (ws_size >= xbf_b + wfrag_b + wf_b + p1_b) {
        k_build_wfrag2<<<1024, 256, 0, stream>>>(W, wfrag);
        k_ab<<<(N_Q + 15) / 16, 512, 0, stream>>>(qp, sp, nb, kp, xbf, wfbuf);
        k_gemm_split<<<391 * 2, 512, 0, stream>>>(wfbuf, wfrag, out, p1);
        k_reduce<<<3125, 256, 0, stream>>>(out, p1);
    } else if (ws_size >= xbf_b + wfrag_b + wf_b) {
        k_build_wfrag2<<<1024, 256, 0, stream>>>(W, wfrag);
        k_ab<<<(N_Q + 15) / 16, 512, 0, stream>>>(qp, sp, nb, kp, xbf, wfbuf);
        k_gemm_full<<<(N_Q + 63) / 64, 512, 0, stream>>>(wfbuf, wfrag, out);
    } else {
        k_build_wfrag<<<960, 256, 0, stream>>>(W, wfrag);
        k_main_fb<<<(N_Q + 15) / 16, 256, 0, stream>>>(qp, sp, nb, kp, xbf, wfrag, out);
    }
}

// Round 12
// 81.161 us; speedup vs baseline: 1.8873x; 1.1134x over previous
//
#include <hip/hip_runtime.h>
#include <hip/hip_bf16.h>

#define N_Q   25000
#define M_S   25000
#define C_INV 128

typedef unsigned short ushortT;
typedef unsigned short us8 __attribute__((ext_vector_type(8)));
typedef unsigned short us4 __attribute__((ext_vector_type(4)));
typedef short s8v __attribute__((ext_vector_type(8)));
typedef float f32x4 __attribute__((ext_vector_type(4)));

#define GAS __attribute__((address_space(1)))
#define LAS __attribute__((address_space(3)))

__device__ __forceinline__ float b2f(ushortT u) {
    unsigned v = ((unsigned)u) << 16;
    return __builtin_bit_cast(float, v);
}
__device__ __forceinline__ ushortT f2b(float f) {
    __hip_bfloat16 h = __float2bfloat16(f);
    return __builtin_bit_cast(ushortT, h);
}

// ---------------- k_prep: [0,3125) convert x -> bf16 ; [3125,4149) build wfrag2 ----------------
// wfrag2: K padded 2048, p = ci*256 + ls*4 + r -> (k=(ls>>4)*4+r, c=ci*16+(ls&15)), 0 for k==15.
// elem o = ((ks*8+db)*64+lane)*8+j holds W_perm[ks*32+(lane>>4)*8+j][db*16+(lane&15)].
__global__ void k_prep(const float* __restrict__ x, ushortT* __restrict__ xb,
                       const float* __restrict__ W, ushortT* __restrict__ wf) {
    if (blockIdx.x < 3125) {
        int i = blockIdx.x * 256 + threadIdx.x;
        const int n4 = (M_S * C_INV) / 4;
        if (i >= n4) return;
        float4 v = ((const float4*)x)[i];
        us4 o;
        o[0] = f2b(v.x); o[1] = f2b(v.y); o[2] = f2b(v.z); o[3] = f2b(v.w);
        ((us4*)xb)[i] = o;
    } else {
        int o = (blockIdx.x - 3125) * 256 + threadIdx.x;
        if (o >= 262144) return;                 // 2048 * 128
        int j   = o & 7;
        int l   = (o >> 3) & 63;
        int db  = (o >> 9) & 7;
        int ks  = o >> 12;                       // 0..63
        int p   = ks * 32 + ((l >> 4) * 8) + j;  // 0..2047
        int ci  = p >> 8;
        int rem = p & 255;
        int ls  = rem >> 2;
        int r   = rem & 3;
        int k   = (ls >> 4) * 4 + r;
        int c   = ci * 16 + (ls & 15);
        int d   = db * 16 + (l & 15);
        wf[o] = (k < 15) ? f2b(W[((size_t)k * 128 + c) * 128 + d]) : (ushortT)0;
    }
}

// ---------------- fallback-only: x converter + old wfrag layout ----------------
__global__ void k_convert_x(const float* __restrict__ x, ushortT* __restrict__ xb) {
    int i = blockIdx.x * 256 + threadIdx.x;
    const int n4 = (M_S * C_INV) / 4;
    if (i >= n4) return;
    float4 v = ((const float4*)x)[i];
    us4 o;
    o[0] = f2b(v.x); o[1] = f2b(v.y); o[2] = f2b(v.z); o[3] = f2b(v.w);
    ((us4*)xb)[i] = o;
}
__global__ void k_build_wfrag(const float* __restrict__ W, ushortT* __restrict__ wf) {
    int o = blockIdx.x * 256 + threadIdx.x;
    if (o >= 1920 * 128) return;
    int j  = o & 7;
    int l  = (o >> 3) & 63;
    int db = (o >> 9) & 7;
    int ks = o >> 12;
    int r  = ks * 32 + ((l >> 4) * 8) + j;
    int d  = db * 16 + (l & 15);
    wf[o] = f2b(W[r * 128 + d]);
}

// ================= K1 (r5-verified): stages A+B, register gather, fragment-major wf =================
__global__ __launch_bounds__(512, 4) void k_ab(
    const float* __restrict__ qp, const float* __restrict__ sp,
    const int* __restrict__ nb, const float* __restrict__ kp,
    const ushortT* __restrict__ xbf, ushortT* __restrict__ wf_out)
{
    __shared__ __align__(16) ushortT s_w[16 * 512];   // 16 KB fragment layout [q][(h>>3)*128 + k*8 + (h&7)]
    __shared__ int s_idx[16 * 32];                    //  2 KB

    const int t   = threadIdx.x;
    const int l   = t & 63;
    const int w   = t >> 6;          // wave 0..7
    const int blk = blockIdx.x;

    // ---- Phase A ----
    {
        const int q  = t >> 5;
        const int h  = t & 31;
        const int qg = blk * 16 + q;
        const int qc = (qg < N_Q) ? qg : (N_Q - 1);
        const float qx = qp[qc * 3 + 0], qy = qp[qc * 3 + 1], qz = qp[qc * 3 + 2];
        int idx = (qg < N_Q) ? nb[qg * 32 + h] : M_S;
        const bool valid = ((unsigned)idx < (unsigned)M_S);
        const int idc = valid ? idx : 0;
        s_idx[q * 32 + h] = idc;
        float px, py, pz;
        if (valid) { px = sp[idc * 3]; py = sp[idc * 3 + 1]; pz = sp[idc * 3 + 2]; }
        else       { px = 1e6f; py = 1e6f; pz = 1e6f; }
        const float rx = px - qx, ry = py - qy, rz = pz - qz;
        #pragma unroll
        for (int k = 0; k < 15; ++k) {
            const float dx = rx - kp[k * 3 + 0];
            const float dy = ry - kp[k * 3 + 1];
            const float dz = rz - kp[k * 3 + 2];
            const float d2 = dx * dx + dy * dy + dz * dz;
            float wv = 1.0f - sqrtf(d2) * (1.0f / 1.2f);
            wv = (wv > 0.0f) ? wv : 0.0f;
            s_w[q * 512 + (h >> 3) * 128 + k * 8 + (h & 7)] = f2b(wv);
        }
        s_w[q * 512 + (h >> 3) * 128 + 15 * 8 + (h & 7)] = 0;
    }
    __syncthreads();

    const int c0 = l & 15;
    const int hg = l >> 4;

    s8v af[2];
    int ridx[2][8];
    #pragma unroll
    for (int qi = 0; qi < 2; ++qi) {
        const int q = w * 2 + qi;
        af[qi] = *(const s8v*)(s_w + q * 512 + hg * 128 + c0 * 8);
        #pragma unroll
        for (int j = 0; j < 8; ++j)
            ridx[qi][j] = s_idx[q * 32 + hg * 8 + j];
    }

    us4* wfo = (us4*)wf_out;

    #pragma unroll
    for (int qi = 0; qi < 2; ++qi) {
        const int qrow = blk * 16 + w * 2 + qi;
        const ushortT* rp[8];
        #pragma unroll
        for (int j = 0; j < 8; ++j)
            rp[j] = xbf + (size_t)ridx[qi][j] * 128 + c0;

        us8 xr[8];   // xr[ci][j] = x[idx[hg*8+j]][ci*16 + c0]
        #pragma unroll
        for (int j = 0; j < 8; ++j) {
            #pragma unroll
            for (int ci = 0; ci < 8; ++ci)
                xr[ci][j] = rp[j][ci * 16];
        }
        #pragma unroll
        for (int ci = 0; ci < 8; ++ci) {
            f32x4 d = __builtin_amdgcn_mfma_f32_16x16x32_bf16(
                af[qi], __builtin_bit_cast(s8v, xr[ci]), (f32x4){0.f, 0.f, 0.f, 0.f}, 0, 0, 0);
            us4 o;
            o[0] = f2b(d[0]); o[1] = f2b(d[1]); o[2] = f2b(d[2]); o[3] = f2b(d[3]);
            wfo[(size_t)qrow * 512 + ci * 64 + l] = o;
        }
    }
}

// ================= K2 v9: Q-tile 32, 256 threads, 782 blocks (3/CU), full-K, direct store =================
// Same verified staging/swizzle/fragment expressions as r5's k_gemm_full; only the row
// blocking is halved so the grid fills the chip (r5/r11 lesson: 391 blocks = 1.5/CU starved).
__global__ __launch_bounds__(256, 4) void k_gemm32(
    const ushortT* __restrict__ wf, const ushortT* __restrict__ wfrag,
    float* __restrict__ out)
{
    __shared__ __align__(16) ushortT sA[2][4096];   // 8 KB each: 32q x 128 elems (4 ks), XOR-swizzled

    const int t    = threadIdx.x;
    const int l    = t & 63;
    const int w    = t >> 6;          // 0..3
    const int tile = blockIdx.x;      // 0..781
    const int n0   = w * 2;           // 0,2,4,6

    auto stage = [&](int c4, int buf) {
        #pragma unroll
        for (int u = 0; u < 2; ++u) {
            const int s    = u * 256 + t;     // 0..511 = 32 q x 16 parts
            const int q    = s >> 4;
            const int part = s & 15;
            const ushortT* src = wf + (size_t)(tile * 32 + q) * 2048 + c4 * 128
                               + ((part ^ (q & 7)) * 8);
            __builtin_amdgcn_global_load_lds((const GAS unsigned int*)(const void*)src,
                                             (LAS unsigned int*)(void*)(&sA[buf][(size_t)s * 8]),
                                             16, 0, 0);
        }
    };

    f32x4 a00 = {0.f,0.f,0.f,0.f}, a01 = {0.f,0.f,0.f,0.f};
    f32x4 a10 = {0.f,0.f,0.f,0.f}, a11 = {0.f,0.f,0.f,0.f};

    stage(0, 0);
    __syncthreads();

    for (int c4 = 0; c4 < 16; ++c4) {
        if (c4 < 15) stage(c4 + 1, (c4 + 1) & 1);
        const ushortT* A = sA[c4 & 1];
        const int q0 = l & 15;
        const int q1 = q0 + 16;
        #pragma unroll
        for (int kk = 0; kk < 4; ++kk) {
            const int ks = c4 * 4 + kk;
            const s8v b0 = *(const s8v*)(wfrag + ((size_t)(ks * 8 + n0    ) * 64 + l) * 8);
            const s8v b1 = *(const s8v*)(wfrag + ((size_t)(ks * 8 + n0 + 1) * 64 + l) * 8);
            const int eo = kk * 32 + (l >> 4) * 8;
            const s8v av0 = *(const s8v*)(A + q0 * 128 + (eo ^ ((q0 & 7) * 8)));
            const s8v av1 = *(const s8v*)(A + q1 * 128 + (eo ^ ((q1 & 7) * 8)));
            a00 = __builtin_amdgcn_mfma_f32_16x16x32_bf16(av0, b0, a00, 0, 0, 0);
            a01 = __builtin_amdgcn_mfma_f32_16x16x32_bf16(av0, b1, a01, 0, 0, 0);
            a10 = __builtin_amdgcn_mfma_f32_16x16x32_bf16(av1, b0, a10, 0, 0, 0);
            a11 = __builtin_amdgcn_mfma_f32_16x16x32_bf16(av1, b1, a11, 0, 0, 0);
        }
        __syncthreads();
    }

    #pragma unroll
    for (int r = 0; r < 4; ++r) {
        const int qa = tile * 32 + (l >> 4) * 4 + r;
        const int qb = qa + 16;
        const int d0 = n0 * 16 + (l & 15);
        if (qa < N_Q) {
            out[(size_t)qa * 128 + d0]      = a00[r];
            out[(size_t)qa * 128 + d0 + 16] = a01[r];
        }
        if (qb < N_Q) {
            out[(size_t)qb * 128 + d0]      = a10[r];
            out[(size_t)qb * 128 + d0 + 16] = a11[r];
        }
    }
}

// ================= fallback: round-1 fused kernel (tiny ws) =================
__global__ __launch_bounds__(256, 2) void k_main_fb(
    const float* __restrict__ qp, const float* __restrict__ sp,
    const int* __restrict__ nb, const float* __restrict__ kp,
    const ushortT* __restrict__ xbf, const ushortT* __restrict__ wfrag,
    float* __restrict__ out)
{
    __shared__ ushortT s_w[16][32][16];
    __shared__ int s_idx[16][32];
    __shared__ __align__(16) ushortT s_wf[16][1928];

    const int t   = threadIdx.x;
    const int blk = blockIdx.x;

    {
        const int q  = t >> 4;
        const int h0 = t & 15;
        const int qg = blk * 16 + q;
        const int qc = (qg < N_Q) ? qg : 0;
        const float qx = qp[qc * 3 + 0], qy = qp[qc * 3 + 1], qz = qp[qc * 3 + 2];
        #pragma unroll
        for (int i = 0; i < 2; ++i) {
            const int h  = h0 + 16 * i;
            int idx = (qg < N_Q) ? nb[qg * 32 + h] : M_S;
            const bool valid = ((unsigned)idx < (unsigned)M_S);
            s_idx[q][h] = valid ? idx : 0;
            float px, py, pz;
            if (valid) { px = sp[idx * 3]; py = sp[idx * 3 + 1]; pz = sp[idx * 3 + 2]; }
            else       { px = 1e6f; py = 1e6f; pz = 1e6f; }
            const float rx = px - qx, ry = py - qy, rz = pz - qz;
            #pragma unroll
            for (int k = 0; k < 15; ++k) {
                const float dx = rx - kp[k * 3 + 0];
                const float dy = ry - kp[k * 3 + 1];
                const float dz = rz - kp[k * 3 + 2];
                const float d2 = dx * dx + dy * dy + dz * dz;
                float wv = 1.0f - sqrtf(d2) * (1.0f / 1.2f);
                wv = (wv > 0.0f) ? wv : 0.0f;
                s_w[q][h][k] = f2b(wv);
            }
            s_w[q][h][15] = 0;
        }
    }
    __syncthreads();

    {
        const int q  = t >> 4;
        const int c0 = (t & 15) * 8;
        float acc[15][8];
        #pragma unroll
        for (int k = 0; k < 15; ++k)
            #pragma unroll
            for (int j = 0; j < 8; ++j) acc[k][j] = 0.0f;

        int idx0 = s_idx[q][0];
        us8 xv = *(const us8*)(xbf + (size_t)idx0 * C_INV + c0);
        for (int h = 0; h < 32; ++h) {
            const us8 xc = xv;
            if (h < 31) {
                int idn = s_idx[q][h + 1];
                xv = *(const us8*)(xbf + (size_t)idn * C_INV + c0);
            }
            const us8 w0 = *(const us8*)&s_w[q][h][0];
            const us8 w1 = *(const us8*)&s_w[q][h][8];
            float xf[8];
            #pragma unroll
            for (int j = 0; j < 8; ++j) xf[j] = b2f(xc[j]);
            #pragma unroll
            for (int k = 0; k < 15; ++k) {
                const float wk = b2f((k < 8) ? w0[k] : w1[k - 8]);
                #pragma unroll
                for (int j = 0; j < 8; ++j) acc[k][j] += wk * xf[j];
            }
        }
        #pragma unroll
        for (int k = 0; k < 15; ++k) {
            us8 o;
            #pragma unroll
            for (int j = 0; j < 8; ++j) o[j] = f2b(acc[k][j]);
            *(us8*)&s_wf[q][k * C_INV + c0] = o;
        }
    }
    __syncthreads();

    {
        const int lane = t & 63;
        const int wv   = t >> 6;
        const int db0  = wv * 2;
        const int arow = lane & 15;
        const int kofs = (lane >> 4) * 8;
        f32x4 acc0 = {0.f, 0.f, 0.f, 0.f};
        f32x4 acc1 = {0.f, 0.f, 0.f, 0.f};
        #pragma unroll 4
        for (int ks = 0; ks < 60; ++ks) {
            s8v a  = *(const s8v*)&s_wf[arow][ks * 32 + kofs];
            s8v b0 = *(const s8v*)(wfrag + ((size_t)(ks * 8 + db0) * 64 + lane) * 8);
            s8v b1 = *(const s8v*)(wfrag + ((size_t)(ks * 8 + db0 + 1) * 64 + lane) * 8);
            acc0 = __builtin_amdgcn_mfma_f32_16x16x32_bf16(a, b0, acc0, 0, 0, 0);
            acc1 = __builtin_amdgcn_mfma_f32_16x16x32_bf16(a, b1, acc1, 0, 0, 0);
        }
        #pragma unroll
        for (int r = 0; r < 4; ++r) {
            const int q  = (lane >> 4) * 4 + r;
            const int qg = blk * 16 + q;
            if (qg < N_Q) {
                out[(size_t)qg * 128 + db0 * 16 + (lane & 15)]       = acc0[r];
                out[(size_t)qg * 128 + (db0 + 1) * 16 + (lane & 15)] = acc1[r];
            }
        }
    }
}

extern "C" void kernel_launch(void* const* d_in, const int* in_sizes, int n_in,
                              void* d_out, int out_size, void* d_ws, size_t ws_size,
                              hipStream_t stream) {
    const float* x  = (const float*)d_in[0];
    const float* qp = (const float*)d_in[1];
    const float* sp = (const float*)d_in[2];
    const int*   nb = (const int*)d_in[3];
    const float* kp = (const float*)d_in[4];
    const float* W  = (const float*)d_in[5];
    float* out = (float*)d_out;

    const size_t xbf_b   = (size_t)M_S * C_INV * 2;        // 6,400,000
    const size_t wfrag_b = (size_t)2048 * 128 * 2;         // 524,288
    const size_t wf_b    = (size_t)25024 * 2048 * 2;       // 102,498,304

    ushortT* xbf   = (ushortT*)d_ws;
    ushortT* wfrag = (ushortT*)((char*)d_ws + xbf_b);
    ushortT* wfbuf = (ushortT*)((char*)d_ws + xbf_b + wfrag_b);

    if (ws_size >= xbf_b + wfrag_b + wf_b) {
        k_prep<<<3125 + 1024, 256, 0, stream>>>(x, xbf, W, wfrag);
        k_ab<<<(N_Q + 15) / 16, 512, 0, stream>>>(qp, sp, nb, kp, xbf, wfbuf);
        k_gemm32<<<(N_Q + 31) / 32, 256, 0, stream>>>(wfbuf, wfrag, out);
    } else {
        k_convert_x<<<3125, 256, 0, stream>>>(x, xbf);
        k_build_wfrag<<<960, 256, 0, stream>>>(W, wfrag);
        k_main_fb<<<(N_Q + 15) / 16, 256, 0, stream>>>(qp, sp, nb, kp, xbf, wfrag, out);
    }
}